// Round 5
// baseline (10620.323 us; speedup 1.0000x reference)
//
#include <hip/hip_runtime.h>
#include <hip/hip_fp16.h>

typedef _Float16 f16;
typedef _Float16 f16x2 __attribute__((ext_vector_type(2)));
typedef _Float16 f16x4 __attribute__((ext_vector_type(4)));
typedef _Float16 f16x8 __attribute__((ext_vector_type(8)));
typedef float f32x4 __attribute__((ext_vector_type(4)));

// ---------------- cast fp32 -> f16 (x4 vectorized) ----------------
__global__ void cast_f32_f16(const float* __restrict__ in, f16* __restrict__ out, int n4) {
    int i = blockIdx.x * blockDim.x + threadIdx.x;
    if (i >= n4) return;
    float4 v = ((const float4*)in)[i];
    f16x4 o;
    o.x = (f16)v.x; o.y = (f16)v.y; o.z = (f16)v.z; o.w = (f16)v.w;
    ((f16x4*)out)[i] = o;
}

// ---------------- pack w_hh for register-resident layout (rotated chunk order) ----
// Thread tid = (g*32+jj)*4 + kq owns w[g*512 + slice*32+jj][kq*128 .. +128).
// Chunk r (0..15) holds logical k-subchunk s = (r + 2*kq) & 15 (bank-conflict-free
// rotated LDS walk on the consumer side).
__global__ void pack_whh_reg(const float* __restrict__ wf, const float* __restrict__ wb,
                             uint* __restrict__ wr) {
    int gidx = blockIdx.x * blockDim.x + threadIdx.x;   // [0, 2*16*512*64)
    if (gidx >= (2 * 16 * 512 * 64)) return;
    int i     = gidx & 63;
    int tid   = (gidx >> 6) & 511;
    int slice = (gidx >> 15) & 15;
    int d     = gidx >> 19;
    int kq = tid & 3, row = tid >> 2, g = row >> 5, jj = row & 31;
    int r = i >> 2, u = i & 3;
    int s = (r + 2 * kq) & 15;
    int j = slice * 32 + jj;
    int k = kq * 128 + s * 8 + u * 2;
    const float* w = d ? wb : wf;
    const float* base = w + (size_t)(g * 512 + j) * 512 + k;
    f16x2 p; p.x = (f16)base[0]; p.y = (f16)base[1];
    wr[gidx] = __builtin_bit_cast(uint, p);
}

// ---------------- input projection GEMM (f16 MFMA, fp32 accum) ----------------
__global__ __launch_bounds__(256)
void gemm_proj(const f16* __restrict__ A, const f16* __restrict__ W,
               const float* __restrict__ bias_f, const float* __restrict__ bias_b,
               f16* __restrict__ C, int K) {
    __shared__ f16 As[128 * 64];
    __shared__ f16 Bs[128 * 64];
    const int m0 = blockIdx.x * 128;
    const int n0 = blockIdx.y * 128;
    const int tid = threadIdx.x;
    const int lane = tid & 63;
    const int wave = tid >> 6;
    const int wm = wave >> 1, wn = wave & 1;
    const int r_in = tid >> 3;
    const int cb   = (tid & 7) * 16;
    f32x4 acc[4][4] = {};

    for (int k0 = 0; k0 < K; k0 += 64) {
#pragma unroll
        for (int c = 0; c < 4; ++c) {
            int row = c * 32 + r_in;
            *(uint4*)((char*)As + c * 4096 + tid * 16) =
                *(const uint4*)((const char*)A + ((size_t)(m0 + row) * K + k0) * 2 + cb);
            *(uint4*)((char*)Bs + c * 4096 + tid * 16) =
                *(const uint4*)((const char*)W + ((size_t)(n0 + row) * K + k0) * 2 + cb);
        }
        __syncthreads();
#pragma unroll
        for (int ks = 0; ks < 2; ++ks) {
            f16x8 af[4], bf[4];
            const int ko = ks * 64 + ((lane >> 4) * 16);
#pragma unroll
            for (int i2 = 0; i2 < 4; ++i2) {
                af[i2] = *(const f16x8*)((const char*)As + (wm * 64 + i2 * 16 + (lane & 15)) * 128 + ko);
                bf[i2] = *(const f16x8*)((const char*)Bs + (wn * 64 + i2 * 16 + (lane & 15)) * 128 + ko);
            }
#pragma unroll
            for (int i2 = 0; i2 < 4; ++i2)
#pragma unroll
                for (int j2 = 0; j2 < 4; ++j2)
                    acc[i2][j2] = __builtin_amdgcn_mfma_f32_16x16x32_f16(af[i2], bf[j2], acc[i2][j2], 0, 0, 0);
        }
        __syncthreads();
    }
#pragma unroll
    for (int i2 = 0; i2 < 4; ++i2) {
        const int row = m0 + wm * 64 + i2 * 16 + ((lane >> 4) << 2);
#pragma unroll
        for (int j2 = 0; j2 < 4; ++j2) {
            const int col = n0 + wn * 64 + j2 * 16 + (lane & 15);
            const float bs = (col < 2048) ? bias_f[col] : bias_b[col - 2048];
#pragma unroll
            for (int r = 0; r < 4; ++r)
                C[(size_t)(row + r) * 4096 + col] = (f16)(acc[i2][j2][r] + bs);
        }
    }
}

// ---------------- LSTM recurrence: dual-direction chain per CU ----------------
__device__ __forceinline__ float sigm(float x) { return 1.f / (1.f + __expf(-x)); }
__device__ __forceinline__ float tanhfast(float x) { return 1.f - 2.f / (__expf(2.f * x) + 1.f); }

__device__ __forceinline__ float fdot2f(uint w2, uint h2, float acc) {
#if __has_builtin(__builtin_amdgcn_fdot2)
    return __builtin_amdgcn_fdot2(__builtin_bit_cast(f16x2, w2),
                                  __builtin_bit_cast(f16x2, h2), acc, false);
#else
    f16x2 a = __builtin_bit_cast(f16x2, w2), b = __builtin_bit_cast(f16x2, h2);
    return fmaf((float)a.y, (float)b.y, fmaf((float)a.x, (float)b.x, acc));
#endif
}

// dot for one dir (weights at compile-time BASE), 2 batches.
template <int BASE>
__device__ __forceinline__ void dot2b(const uint (&w)[128], const f16 (*hl)[512],
                                      int kq, float& a0, float& a1) {
    const char* h0 = (const char*)&hl[0][0] + (kq << 8);
    const char* h1 = (const char*)&hl[1][0] + (kq << 8);
    float x0 = 0.f, x1 = 0.f;
#pragma unroll
    for (int r = 0; r < 16; ++r) {
        const int s4 = (((r + (kq << 1)) & 15) << 4);
        uint4 hv0 = *(const uint4*)(h0 + s4);
        uint4 hv1 = *(const uint4*)(h1 + s4);
        x0 = fdot2f(w[BASE + r * 4 + 0], hv0.x, x0);
        x0 = fdot2f(w[BASE + r * 4 + 1], hv0.y, x0);
        x0 = fdot2f(w[BASE + r * 4 + 2], hv0.z, x0);
        x0 = fdot2f(w[BASE + r * 4 + 3], hv0.w, x0);
        x1 = fdot2f(w[BASE + r * 4 + 0], hv1.x, x1);
        x1 = fdot2f(w[BASE + r * 4 + 1], hv1.y, x1);
        x1 = fdot2f(w[BASE + r * 4 + 2], hv1.z, x1);
        x1 = fdot2f(w[BASE + r * 4 + 3], hv1.w, x1);
    }
    a0 = x0; a1 = x1;
}

// Grid = 256 WGs x 512 threads (1 WG/CU). 16 groups x 16 slice-WGs.
// Group gid owns batches {2gid, 2gid+1}, BOTH dirs. Thread holds w[128] (both dirs).
// Per iter: fwd compute/publish -> consume bwd h (hidden) -> bwd compute/publish
// -> consume fwd h (hidden). Relaxed agent atomics only (L3, no cache maintenance);
// __syncthreads' vmcnt-drain orders stores before the arrival fetch_add.
#define PHASE(D, BASE, CC, X0, X1, X2, X3, T, CTR)                                  \
    {                                                                               \
        float a0, a1;                                                               \
        dot2b<BASE>(w, h_lds[D], kq, a0, a1);                                       \
        a0 += __shfl_xor(a0, 1); a0 += __shfl_xor(a0, 2);                           \
        a1 += __shfl_xor(a1, 1); a1 += __shfl_xor(a1, 2);                           \
        if (kq == 0) *(float2*)&gbuf[tid >> 2][0] = make_float2(a0, a1);            \
        __syncthreads();                                                            \
        if (tid < 64) {                                                             \
            float gi = gbuf[ajj][ab]      + X0;                                     \
            float gf = gbuf[32 + ajj][ab] + X1;                                     \
            float gg = gbuf[64 + ajj][ab] + X2;                                     \
            float go = gbuf[96 + ajj][ab] + X3;                                     \
            float iv = sigm(gi), fv = sigm(gf), ov = sigm(go), gv = tanhfast(gg);   \
            CC = fv * CC + iv * gv;                                                 \
            float hn = ov * tanhfast(CC);                                           \
            float ho = __shfl_xor(hn, 1);                                           \
            if ((tid & 1) == 0) {                                                   \
                f16x2 pv; pv.x = (f16)hn; pv.y = (f16)ho;                           \
                const int uidx = ((((par * 2 + D) * 16 + gid) * 2 + ab) << 8)       \
                                 + slice * 16 + (ajj >> 1);                         \
                __hip_atomic_store(hx + uidx, __builtin_bit_cast(uint, pv),         \
                                   __ATOMIC_RELAXED, __HIP_MEMORY_SCOPE_AGENT);     \
            }                                                                       \
            out[((size_t)((gid * 2 + ab) * 512 + (T)) << 10) + ((D) << 9)           \
                + slice * 32 + ajj] = (OutT)hn;                                     \
        }                                                                           \
        __syncthreads();                                                            \
        if (tid == 0)                                                               \
            __hip_atomic_fetch_add(CTR, 1u, __ATOMIC_RELAXED,                       \
                                   __HIP_MEMORY_SCOPE_AGENT);                       \
    }

#define CONSUME(D, P, TARGET, CTR)                                                  \
    {                                                                               \
        if (tid == 0) {                                                             \
            int guard = 0;                                                          \
            while (__hip_atomic_load(CTR, __ATOMIC_RELAXED,                         \
                                     __HIP_MEMORY_SCOPE_AGENT) < (unsigned)(TARGET) \
                   && guard < (1 << 22)) {                                          \
                __builtin_amdgcn_s_sleep(1); ++guard;                               \
            }                                                                       \
        }                                                                           \
        __syncthreads();                                                            \
        {                                                                           \
            const uint v = __hip_atomic_load(                                       \
                hx + (((((P) * 2 + (D)) * 16 + gid)) << 9) + tid,                   \
                __ATOMIC_RELAXED, __HIP_MEMORY_SCOPE_AGENT);                        \
            *(uint*)&h_lds[D][tid >> 8][(tid & 255) * 2] = v;                       \
        }                                                                           \
        __syncthreads();                                                            \
    }

template <typename OutT>
__global__ __launch_bounds__(512, 2)
void lstm_rec(const f16* __restrict__ xp,      // (32*512, 4096): n = d*2048 + g*512 + j
              const uint* __restrict__ wr,     // [2][16][512][64]
              uint* __restrict__ hx,           // [2 par][2 d][16 grp][2 b][256 u32] = 128KB
              unsigned* __restrict__ cnt,      // [32] zeroed before launch
              OutT* __restrict__ out) {        // (32*512, 1024): n = d*512 + j
    __shared__ f16  h_lds[2][2][512];          // [dir][batch][j]
    __shared__ float gbuf[128][2];
    const int tid = threadIdx.x;
    const int bid = blockIdx.x;
    const int xcd   = bid & 7;
    const int idx   = bid >> 3;                 // 0..31
    const int gid   = xcd * 2 + (idx >> 4);     // 0..15
    const int slice = idx & 15;
    const int kq  = tid & 3;
    const int ab  = (tid >> 5) & 1, ajj = tid & 31;   // activation role (tid<64)

    // both dirs' weights -> registers (once); asm pin prevents in-loop reload
    uint w[128];
    {
        const uint4* wp0 = (const uint4*)(wr + (((size_t)0 * 16 + slice) * 512 + tid) * 64);
        const uint4* wp1 = (const uint4*)(wr + (((size_t)1 * 16 + slice) * 512 + tid) * 64);
#pragma unroll
        for (int i = 0; i < 16; ++i) {
            uint4 v = wp0[i];
            w[i * 4 + 0] = v.x; w[i * 4 + 1] = v.y; w[i * 4 + 2] = v.z; w[i * 4 + 3] = v.w;
        }
#pragma unroll
        for (int i = 0; i < 16; ++i) {
            uint4 v = wp1[i];
            w[64 + i * 4 + 0] = v.x; w[64 + i * 4 + 1] = v.y;
            w[64 + i * 4 + 2] = v.z; w[64 + i * 4 + 3] = v.w;
        }
#pragma unroll
        for (int i = 0; i < 128; ++i) asm volatile("" : "+v"(w[i]));
    }
    ((uint2*)h_lds)[tid] = make_uint2(0u, 0u);   // h0 = 0 (both dirs, both batches)
    float cc_f = 0.f, cc_b = 0.f;
    unsigned* cf = cnt + gid * 2;
    unsigned* cb = cnt + gid * 2 + 1;
    __syncthreads();

    for (int s = 0; s < 512; ++s) {
        const int tf = s, tb = 511 - s, par = s & 1;
        float xf0 = 0.f, xf1 = 0.f, xf2 = 0.f, xf3 = 0.f;
        float xb0 = 0.f, xb1 = 0.f, xb2 = 0.f, xb3 = 0.f;
        if (tid < 64) {
            const f16* xrf = xp + ((size_t)((gid * 2 + ab) * 512 + tf) << 12) + slice * 32 + ajj;
            const f16* xrb = xp + ((size_t)((gid * 2 + ab) * 512 + tb) << 12) + 2048 + slice * 32 + ajj;
            xf0 = (float)xrf[0]; xf1 = (float)xrf[512]; xf2 = (float)xrf[1024]; xf3 = (float)xrf[1536];
            xb0 = (float)xrb[0]; xb1 = (float)xrb[512]; xb2 = (float)xrb[1024]; xb3 = (float)xrb[1536];
        }

        PHASE(0, 0, cc_f, xf0, xf1, xf2, xf3, tf, cf)          // fwd step s, publish
        if (s > 0)
            CONSUME(1, (s - 1) & 1, 16 * s, cb)                // bwd h[s-1] (hidden under fwd)
        PHASE(1, 64, cc_b, xb0, xb1, xb2, xb3, tb, cb)         // bwd step s, publish
        if (s < 511)
            CONSUME(0, par, 16 * (s + 1), cf)                  // fwd h[s] (hidden under bwd)
    }
}

// ---------------- launch ----------------
extern "C" void kernel_launch(void* const* d_in, const int* in_sizes, int n_in,
                              void* d_out, int out_size, void* d_ws, size_t ws_size,
                              hipStream_t stream) {
    const float* x      = (const float*)d_in[0];
    const float* wih_f0 = (const float*)d_in[1];
    const float* bih_f0 = (const float*)d_in[2];
    const float* whh_f0 = (const float*)d_in[3];
    const float* wih_b0 = (const float*)d_in[4];
    const float* bih_b0 = (const float*)d_in[5];
    const float* whh_b0 = (const float*)d_in[6];
    const float* wih_f1 = (const float*)d_in[7];
    const float* bih_f1 = (const float*)d_in[8];
    const float* whh_f1 = (const float*)d_in[9];
    const float* wih_b1 = (const float*)d_in[10];
    const float* bih_b1 = (const float*)d_in[11];
    const float* whh_b1 = (const float*)d_in[12];

    char* ws = (char*)d_ws;
    f16*   xh   = (f16*)(ws);                       // 16 MB (dead after gemm L0)
    uint*  hx   = (uint*)(ws);                      // 128 KB, reuses dead xh region
    unsigned* cnt = (unsigned*)(ws + 131072);       // 128 B, also inside xh region
    f16*   wih0 = (f16*)(ws + 16777216);            // 4 MB
    f16*   wih1 = (f16*)(ws + 20971520);            // 8 MB
    uint*  wr0  = (uint*)(ws + 29360128);           // 4 MB
    uint*  wr1  = (uint*)(ws + 33554432);           // 4 MB
    f16*   xp   = (f16*)(ws + 37748736);            // 128 MB
    f16*   interh = (f16*)d_out;                    // inter-layer buffer inside d_out

    auto cast = [&](const float* in, f16* o, int n) {
        int n4 = n / 4;
        cast_f32_f16<<<(n4 + 255) / 256, 256, 0, stream>>>(in, o, n4);
    };
    cast(x, xh, 8388608);
    cast(wih_f0, wih0, 1048576);
    cast(wih_b0, wih0 + 1048576, 1048576);
    cast(wih_f1, wih1, 2097152);
    cast(wih_b1, wih1 + 2097152, 2097152);
    pack_whh_reg<<<4096, 256, 0, stream>>>(whh_f0, whh_b0, wr0);
    pack_whh_reg<<<4096, 256, 0, stream>>>(whh_f1, whh_b1, wr1);

    // layer 0
    gemm_proj<<<dim3(128, 32), 256, 0, stream>>>(xh, wih0, bih_f0, bih_b0, xp, 512);
    hipMemsetAsync(cnt, 0, 128, stream);
    lstm_rec<f16><<<256, 512, 0, stream>>>(xp, wr0, hx, cnt, interh);
    // layer 1
    gemm_proj<<<dim3(128, 32), 256, 0, stream>>>(interh, wih1, bih_f1, bih_b1, xp, 1024);
    hipMemsetAsync(cnt, 0, 128, stream);
    lstm_rec<float><<<256, 512, 0, stream>>>(xp, wr1, hx, cnt, (float*)d_out);
}

// Round 6
// 3453.095 us; speedup vs baseline: 3.0756x; 3.0756x over previous
//
#include <hip/hip_runtime.h>
#include <hip/hip_fp16.h>

typedef _Float16 f16;
typedef _Float16 f16x2 __attribute__((ext_vector_type(2)));
typedef _Float16 f16x4 __attribute__((ext_vector_type(4)));
typedef _Float16 f16x8 __attribute__((ext_vector_type(8)));
typedef float f32x4 __attribute__((ext_vector_type(4)));

// ---------------- cast fp32 -> f16 (x4 vectorized) ----------------
__global__ void cast_f32_f16(const float* __restrict__ in, f16* __restrict__ out, int n4) {
    int i = blockIdx.x * blockDim.x + threadIdx.x;
    if (i >= n4) return;
    float4 v = ((const float4*)in)[i];
    f16x4 o;
    o.x = (f16)v.x; o.y = (f16)v.y; o.z = (f16)v.z; o.w = (f16)v.w;
    ((f16x4*)out)[i] = o;
}

// ---------------- pack w_hh for register-resident layout (rotated chunk order) ----
// Thread tid = (g*32+jj)*4 + kq owns w[g*512 + slice*32+jj][kq*128 .. +128).
// Chunk r (0..15) holds logical k-subchunk s = (r + 2*kq) & 15 (bank-conflict-free
// rotated LDS walk on the consumer side).
__global__ void pack_whh_reg(const float* __restrict__ wf, const float* __restrict__ wb,
                             uint* __restrict__ wr) {
    int gidx = blockIdx.x * blockDim.x + threadIdx.x;   // [0, 2*16*512*64)
    if (gidx >= (2 * 16 * 512 * 64)) return;
    int i     = gidx & 63;
    int tid   = (gidx >> 6) & 511;
    int slice = (gidx >> 15) & 15;
    int d     = gidx >> 19;
    int kq = tid & 3, row = tid >> 2, g = row >> 5, jj = row & 31;
    int r = i >> 2, u = i & 3;
    int s = (r + 2 * kq) & 15;
    int j = slice * 32 + jj;
    int k = kq * 128 + s * 8 + u * 2;
    const float* w = d ? wb : wf;
    const float* base = w + (size_t)(g * 512 + j) * 512 + k;
    f16x2 p; p.x = (f16)base[0]; p.y = (f16)base[1];
    wr[gidx] = __builtin_bit_cast(uint, p);
}

// ---------------- input projection GEMM (f16 MFMA, fp32 accum) ----------------
__global__ __launch_bounds__(256)
void gemm_proj(const f16* __restrict__ A, const f16* __restrict__ W,
               const float* __restrict__ bias_f, const float* __restrict__ bias_b,
               f16* __restrict__ C, int K) {
    __shared__ f16 As[128 * 64];
    __shared__ f16 Bs[128 * 64];
    const int m0 = blockIdx.x * 128;
    const int n0 = blockIdx.y * 128;
    const int tid = threadIdx.x;
    const int lane = tid & 63;
    const int wave = tid >> 6;
    const int wm = wave >> 1, wn = wave & 1;
    const int r_in = tid >> 3;
    const int cb   = (tid & 7) * 16;
    f32x4 acc[4][4] = {};

    for (int k0 = 0; k0 < K; k0 += 64) {
#pragma unroll
        for (int c = 0; c < 4; ++c) {
            int row = c * 32 + r_in;
            *(uint4*)((char*)As + c * 4096 + tid * 16) =
                *(const uint4*)((const char*)A + ((size_t)(m0 + row) * K + k0) * 2 + cb);
            *(uint4*)((char*)Bs + c * 4096 + tid * 16) =
                *(const uint4*)((const char*)W + ((size_t)(n0 + row) * K + k0) * 2 + cb);
        }
        __syncthreads();
#pragma unroll
        for (int ks = 0; ks < 2; ++ks) {
            f16x8 af[4], bf[4];
            const int ko = ks * 64 + ((lane >> 4) * 16);
#pragma unroll
            for (int i2 = 0; i2 < 4; ++i2) {
                af[i2] = *(const f16x8*)((const char*)As + (wm * 64 + i2 * 16 + (lane & 15)) * 128 + ko);
                bf[i2] = *(const f16x8*)((const char*)Bs + (wn * 64 + i2 * 16 + (lane & 15)) * 128 + ko);
            }
#pragma unroll
            for (int i2 = 0; i2 < 4; ++i2)
#pragma unroll
                for (int j2 = 0; j2 < 4; ++j2)
                    acc[i2][j2] = __builtin_amdgcn_mfma_f32_16x16x32_f16(af[i2], bf[j2], acc[i2][j2], 0, 0, 0);
        }
        __syncthreads();
    }
#pragma unroll
    for (int i2 = 0; i2 < 4; ++i2) {
        const int row = m0 + wm * 64 + i2 * 16 + ((lane >> 4) << 2);
#pragma unroll
        for (int j2 = 0; j2 < 4; ++j2) {
            const int col = n0 + wn * 64 + j2 * 16 + (lane & 15);
            const float bs = (col < 2048) ? bias_f[col] : bias_b[col - 2048];
#pragma unroll
            for (int r = 0; r < 4; ++r)
                C[(size_t)(row + r) * 4096 + col] = (f16)(acc[i2][j2][r] + bs);
        }
    }
}

// ---------------- LSTM recurrence: reg-resident weights, flag-based L3 sync -------
__device__ __forceinline__ float sigm(float x) { return 1.f / (1.f + __expf(-x)); }
__device__ __forceinline__ float tanhfast(float x) { return 1.f - 2.f / (__expf(2.f * x) + 1.f); }

__device__ __forceinline__ float fdot2f(uint w2, uint h2, float acc) {
#if __has_builtin(__builtin_amdgcn_fdot2)
    return __builtin_amdgcn_fdot2(__builtin_bit_cast(f16x2, w2),
                                  __builtin_bit_cast(f16x2, h2), acc, false);
#else
    f16x2 a = __builtin_bit_cast(f16x2, w2), b = __builtin_bit_cast(f16x2, h2);
    return fmaf((float)a.y, (float)b.y, fmaf((float)a.x, (float)b.x, acc));
#endif
}

// Grid = 256 WGs x 512 threads (1 WG/CU, all resident -> spin-safe).
// WG = (dir d, batch-group bg of 4, j-slice of 32). Group = 16 slice-WGs of (d,bg).
// Sync: h published via relaxed agent u32 stores (L3); __syncthreads' vmcnt-drain
// acks them; then ONE relaxed flag store (step stamp) per WG on its own 128B line.
// Consumers: 16 lanes poll the 16 slice flags in parallel (no RMW convoy, no
// fetch_add RTT), then bulk-read h. Flag values are monotone; hx double-buffered
// by step parity; writer of par-slot step s+2 is gated behind all readers of step
// s by the flag chain (same safety argument as the counter protocol).
template <typename OutT>
__global__ __launch_bounds__(512)
void lstm_rec(const f16* __restrict__ xp,      // (32*512, 4096): n = d*2048 + g*512 + j
              const uint* __restrict__ wr,     // [2][16][512][64]
              uint* __restrict__ hx,           // [2 par][2 d][8 bg][4 b][256 u32]
              uint* __restrict__ flags,        // [2 par][2 d][8 bg][16 slice] x 32-u32 stride
              OutT* __restrict__ out) {        // (32*512, 1024): n = d*512 + j
    __shared__ f16  h_lds[4][512];
    __shared__ float gbuf[128][4];
    const int tid = threadIdx.x;
    const int bid = blockIdx.x;
    const int xcd   = bid & 7;
    const int idx   = bid >> 3;                 // 0..31
    const int gid   = xcd * 2 + (idx >> 4);     // 0..15
    const int slice = idx & 15;
    const int d  = gid >> 3;
    const int bg = gid & 7;
    const int kq  = tid & 3;
    const int ab  = tid >> 5, ajj = tid & 31;   // activation role (tid<128)

    // weights -> registers (once); asm pin prevents re-materializing loads in-loop
    uint w[64];
    {
        const uint4* wp = (const uint4*)(wr + (((size_t)d * 16 + slice) * 512 + tid) * 64);
#pragma unroll
        for (int i = 0; i < 16; ++i) {
            uint4 v = wp[i];
            w[i * 4 + 0] = v.x; w[i * 4 + 1] = v.y; w[i * 4 + 2] = v.z; w[i * 4 + 3] = v.w;
        }
#pragma unroll
        for (int i = 0; i < 64; ++i) asm volatile("" : "+v"(w[i]));
    }
    ((uint2*)h_lds)[tid] = make_uint2(0u, 0u);   // h0 = 0
    float cc = 0.f;                               // c state (activation lanes)
    __syncthreads();

    for (int step = 0; step < 512; ++step) {
        const int t = d ? (511 - step) : step;
        const int par = step & 1;

        // xp prefetch for activation lanes (latency hidden under dot)
        float xg0 = 0.f, xg1 = 0.f, xg2 = 0.f, xg3 = 0.f;
        if (tid < 128) {
            const f16* xr = xp + ((size_t)((bg * 4 + ab) * 512 + t) << 12) + (d << 11)
                            + slice * 32 + ajj;
            xg0 = (float)xr[0];
            xg1 = (float)xr[512];
            xg2 = (float)xr[1024];
            xg3 = (float)xr[1536];
        }

        // dot: gate partial over this thread's k-quarter, 4 batches.
        // Rotated chunk walk s=(r+2kq)&15 -> the 4 kq quarters hit different banks.
        float acc[4];
#pragma unroll
        for (int b = 0; b < 4; ++b) {
            float a = 0.f;
            const char* hb = (const char*)&h_lds[b][0] + (kq << 8);
#pragma unroll
            for (int r = 0; r < 16; ++r) {
                const int s = (r + (kq << 1)) & 15;
                uint4 hv = *(const uint4*)(hb + (s << 4));
                a = fdot2f(w[r * 4 + 0], hv.x, a);
                a = fdot2f(w[r * 4 + 1], hv.y, a);
                a = fdot2f(w[r * 4 + 2], hv.z, a);
                a = fdot2f(w[r * 4 + 3], hv.w, a);
            }
            acc[b] = a;
        }
#pragma unroll
        for (int b = 0; b < 4; ++b) {
            acc[b] += __shfl_xor(acc[b], 1);
            acc[b] += __shfl_xor(acc[b], 2);
        }
        if (kq == 0)
            *(float4*)&gbuf[tid >> 2][0] = make_float4(acc[0], acc[1], acc[2], acc[3]);
        __syncthreads();

        if (tid < 128) {
            float gi = gbuf[ajj][ab]      + xg0;
            float gf = gbuf[32 + ajj][ab] + xg1;
            float gg = gbuf[64 + ajj][ab] + xg2;
            float go = gbuf[96 + ajj][ab] + xg3;
            float iv = sigm(gi), fv = sigm(gf), ov = sigm(go), gv = tanhfast(gg);
            cc = fv * cc + iv * gv;
            float hn = ov * tanhfast(cc);
            // pair lanes -> one relaxed agent atomic u32 store per even lane (lands at L3)
            float ho = __shfl_xor(hn, 1);
            if ((tid & 1) == 0) {
                f16x2 pv; pv.x = (f16)hn; pv.y = (f16)ho;
                const int uidx = ((((par * 2 + d) * 8 + bg) * 4 + ab) << 8)
                                 + slice * 16 + (ajj >> 1);
                __hip_atomic_store(hx + uidx, __builtin_bit_cast(uint, pv),
                                   __ATOMIC_RELAXED, __HIP_MEMORY_SCOPE_AGENT);
            }
            out[((size_t)((bg * 4 + ab) * 512 + t) << 10) + (d << 9) + slice * 32 + ajj] = (OutT)hn;
        }
        __syncthreads();   // vmcnt(0) drain: h stores L3-acked before the flag

        // publish flag: this (group, slice) finished step (stamp = step+1)
        if (tid == 0) {
            const uint fidx = ((((par * 2 + d) * 8 + bg) * 16 + slice)) * 32;  // 128B stride
            __hip_atomic_store(flags + fidx, (uint)(step + 1),
                               __ATOMIC_RELAXED, __HIP_MEMORY_SCOPE_AGENT);
        }

        if (step != 511) {
            // wait for all 16 slice flags of this (par, group): 16 parallel pollers
            if (tid < 16) {
                const uint* fp = flags + ((((par * 2 + d) * 8 + bg) * 16 + tid)) * 32;
                int guard = 0;
                while (__hip_atomic_load(fp, __ATOMIC_RELAXED, __HIP_MEMORY_SCOPE_AGENT)
                           < (uint)(step + 1)
                       && guard < (1 << 22)) {
                    __builtin_amdgcn_s_sleep(1);
                    ++guard;
                }
            }
            __syncthreads();

            // read full group h (4 b x 512) -> LDS (linear layout) for next step
            {
                const int hb2 = tid >> 7;       // 0..3
                const int k4  = tid & 127;      // u64 index within batch row
                const unsigned long long hv8 = __hip_atomic_load(
                    (const unsigned long long*)hx
                        + ((((par * 2 + d) * 8 + bg) * 4 + hb2) << 7) + k4,
                    __ATOMIC_RELAXED, __HIP_MEMORY_SCOPE_AGENT);
                *(unsigned long long*)&h_lds[hb2][k4 * 4] = hv8;
            }
            __syncthreads();
        }
    }
}

// ---------------- launch ----------------
extern "C" void kernel_launch(void* const* d_in, const int* in_sizes, int n_in,
                              void* d_out, int out_size, void* d_ws, size_t ws_size,
                              hipStream_t stream) {
    const float* x      = (const float*)d_in[0];
    const float* wih_f0 = (const float*)d_in[1];
    const float* bih_f0 = (const float*)d_in[2];
    const float* whh_f0 = (const float*)d_in[3];
    const float* wih_b0 = (const float*)d_in[4];
    const float* bih_b0 = (const float*)d_in[5];
    const float* whh_b0 = (const float*)d_in[6];
    const float* wih_f1 = (const float*)d_in[7];
    const float* bih_f1 = (const float*)d_in[8];
    const float* whh_f1 = (const float*)d_in[9];
    const float* wih_b1 = (const float*)d_in[10];
    const float* bih_b1 = (const float*)d_in[11];
    const float* whh_b1 = (const float*)d_in[12];

    char* ws = (char*)d_ws;
    f16*   xh   = (f16*)(ws);                       // 16 MB (dead after gemm L0)
    uint*  hx   = (uint*)(ws);                      // 128 KB, reuses dead xh region
    uint*  flags = (uint*)(ws + 131072);            // 64 KB (512 slots x 128B stride)
    f16*   wih0 = (f16*)(ws + 16777216);            // 4 MB
    f16*   wih1 = (f16*)(ws + 20971520);            // 8 MB
    uint*  wr0  = (uint*)(ws + 29360128);           // 4 MB
    uint*  wr1  = (uint*)(ws + 33554432);           // 4 MB
    f16*   xp   = (f16*)(ws + 37748736);            // 128 MB
    f16*   interh = (f16*)d_out;                    // inter-layer buffer inside d_out

    auto cast = [&](const float* in, f16* o, int n) {
        int n4 = n / 4;
        cast_f32_f16<<<(n4 + 255) / 256, 256, 0, stream>>>(in, o, n4);
    };
    cast(x, xh, 8388608);
    cast(wih_f0, wih0, 1048576);
    cast(wih_b0, wih0 + 1048576, 1048576);
    cast(wih_f1, wih1, 2097152);
    cast(wih_b1, wih1 + 2097152, 2097152);
    pack_whh_reg<<<4096, 256, 0, stream>>>(whh_f0, whh_b0, wr0);
    pack_whh_reg<<<4096, 256, 0, stream>>>(whh_f1, whh_b1, wr1);

    // layer 0
    gemm_proj<<<dim3(128, 32), 256, 0, stream>>>(xh, wih0, bih_f0, bih_b0, xp, 512);
    hipMemsetAsync(flags, 0, 65536, stream);
    lstm_rec<f16><<<256, 512, 0, stream>>>(xp, wr0, hx, flags, interh);
    // layer 1
    gemm_proj<<<dim3(128, 32), 256, 0, stream>>>(interh, wih1, bih_f1, bih_b1, xp, 1024);
    hipMemsetAsync(flags, 0, 65536, stream);
    lstm_rec<float><<<256, 512, 0, stream>>>(xp, wr1, hx, flags, (float*)d_out);
}